// Round 11
// baseline (308.351 us; speedup 1.0000x reference)
//
#include <hip/hip_runtime.h>

#define G 4
#define NBATCH 8
#define HIN 128
#define HD 2324
#define NW 36864
#define NO 36928   // NW + 64 biases
#define NO4 (NO / 4)        // 9232
#define GIN 64
#define GOUT 64
#define HIMG 64
#define WIMG 64
#define CIN 256
#define DSPLIT 8
#define DCHUNK 292          // 7*292 + 280 = 2324; all chunks %4==0

typedef __attribute__((ext_vector_type(8))) short bf16x8;
typedef __attribute__((ext_vector_type(4))) float f32x4;

__device__ inline unsigned short bf16rne(float f) {
  union { float f; unsigned u; } x; x.f = f;
  unsigned r = (x.u + 0x7FFF + ((x.u >> 16) & 1)) >> 16;
  return (unsigned short)r;
}
__device__ inline float bflo2f(unsigned u) {
  union { unsigned u; float f; } x; x.u = u << 16; return x.f;
}
__device__ inline float bfhi2f(unsigned u) {
  union { unsigned u; float f; } x; x.u = u & 0xFFFF0000u; return x.f;
}

#define FMA_D(wv, hoff)                                   \
  {                                                       \
    _Pragma("unroll")                                     \
    for (int b = 0; b < NBATCH; ++b) {                    \
      float hv = hh[(hoff) * 8 + b];                      \
      acc[b][0] = fmaf(hv, (wv)[0], acc[b][0]);           \
      acc[b][1] = fmaf(hv, (wv)[1], acc[b][1]);           \
      acc[b][2] = fmaf(hv, (wv)[2], acc[b][2]);           \
      acc[b][3] = fmaf(hv, (wv)[3], acc[b][3]);           \
    }                                                     \
  }

// K2: partial_bf[ds][gb][b-row o] = bf16(sum_{d in chunk ds} h*W2)
// Non-atomic split-K; nontemporal W2 stream; bf16 partial store (halves
// the partial round-trip, fits L2/L3 for wprep).
__global__ __launch_bounds__(256) void k2_hyper_l2(
    const float* __restrict__ h_t, const float* __restrict__ W2,
    short* __restrict__ partial_bf) {
  int g = blockIdx.y, ds = blockIdx.z;
  int o4 = blockIdx.x * 256 + threadIdx.x;
  bool active = (o4 < NO4);
  if (!active) o4 = NO4 - 1;
  const f32x4* W2g = (const f32x4*)(W2 + (size_t)g * HD * NO) + o4;
  const float* hg = h_t + (size_t)g * HD * 8;
  int d0 = ds * DCHUNK;
  int d1 = d0 + DCHUNK; if (d1 > HD) d1 = HD;
  int nd = d1 - d0;                        // multiple of 4

  f32x4 acc[NBATCH] = {};
  const size_t WS = NO4;
  const f32x4* Wp = W2g + (size_t)d0 * WS;
  f32x4 w0 = __builtin_nontemporal_load(Wp);
  f32x4 w1 = __builtin_nontemporal_load(Wp + WS);
  f32x4 w2 = __builtin_nontemporal_load(Wp + 2 * WS);
  f32x4 w3 = __builtin_nontemporal_load(Wp + 3 * WS);
  int dd = 0;
  for (; dd < nd - 4; dd += 4) {
    const f32x4* Wn = Wp + (size_t)(dd + 4) * WS;
    f32x4 n0 = __builtin_nontemporal_load(Wn);
    f32x4 n1 = __builtin_nontemporal_load(Wn + WS);
    f32x4 n2 = __builtin_nontemporal_load(Wn + 2 * WS);
    f32x4 n3 = __builtin_nontemporal_load(Wn + 3 * WS);
    const float* hh = hg + (size_t)(d0 + dd) * 8;   // 32 contiguous f32
    FMA_D(w0, 0) FMA_D(w1, 1) FMA_D(w2, 2) FMA_D(w3, 3)
    w0 = n0; w1 = n1; w2 = n2; w3 = n3;
  }
  {
    const float* hh = hg + (size_t)(d0 + dd) * 8;
    FMA_D(w0, 0) FMA_D(w1, 1) FMA_D(w2, 2) FMA_D(w3, 3)
  }

  if (active) {
    size_t base = ((size_t)ds * G * NBATCH + g * NBATCH) * (size_t)NO;
#pragma unroll
    for (int b = 0; b < NBATCH; ++b) {
      uint2 v;
      v.x = (unsigned)bf16rne(acc[b][0]) | ((unsigned)bf16rne(acc[b][1]) << 16);
      v.y = (unsigned)bf16rne(acc[b][2]) | ((unsigned)bf16rne(acc[b][3]) << 16);
      *(uint2*)(partial_bf + base + (size_t)b * NO + (size_t)o4 * 4) = v;
    }
  }
}

// wprep: coalesced uint2 reads of all 8 bf16 partials (+b2 f32), reduce in
// f32 regs, transpose to [k][o][c] via padded LDS, coalesced store.
// grid (5, 32): x<4 -> weights for o0=x*16; x==4 -> bias.
__global__ __launch_bounds__(256) void k_wprep(
    const short* __restrict__ partial_bf, const float* __restrict__ b2,
    short* __restrict__ wbf, float* __restrict__ bias_f) {
  int gb = blockIdx.y;
  int g = gb >> 3;
  int tid = threadIdx.x;
  if (blockIdx.x == 4) {
    if (tid < GOUT) {
      float s = b2[(size_t)g * NO + NW + tid];
#pragma unroll
      for (int ds = 0; ds < DSPLIT; ++ds) {
        unsigned short pv = (unsigned short)
            partial_bf[((size_t)ds * G * NBATCH + gb) * NO + NW + tid];
        s += bflo2f(pv);
      }
      bias_f[gb * GOUT + tid] = s;
    }
    return;
  }
  __shared__ short lds[9 * 1056];          // padded k-planes
  int o0 = blockIdx.x * 16;
  const f32x4* b2p = (const f32x4*)(b2 + (size_t)g * NO) + o0 * 144;
  const uint2* pbase = (const uint2*)partial_bf + (size_t)gb * NO4 + o0 * 144;
#pragma unroll
  for (int j = 0; j < 9; ++j) {
    int idx4 = tid + j * 256;              // [0, 2304)
    f32x4 s = b2p[idx4];
#pragma unroll
    for (int ds = 0; ds < DSPLIT; ++ds) {
      uint2 v = pbase[(size_t)ds * G * NBATCH * NO4 + idx4];  // coalesced 8B
      s[0] += bflo2f(v.x); s[1] += bfhi2f(v.x);
      s[2] += bflo2f(v.y); s[3] += bfhi2f(v.y);
    }
    int flbase = idx4 * 4;                 // local f in [0, 9216)
#pragma unroll
    for (int e = 0; e < 4; ++e) {
      int fl = flbase + e;
      int ol = fl / 576;
      int rest = fl - ol * 576;
      int c = rest / 9, k = rest - c * 9;
      lds[k * 1056 + ol * 64 + c] = (short)bf16rne(s[e]);
    }
  }
  __syncthreads();
  short* wout = wbf + (size_t)gb * NW;     // [k][o][c], k-plane = 4096 shorts
#pragma unroll
  for (int j = 0; j < 9; ++j) {
    int u = tid + j * 256;                 // uint2 index [0, 2304)
    int k = u >> 8, rem = u & 255;         // 256 uint2 per k-plane (16 o's)
    ((uint2*)(wout + (size_t)k * 4096 + o0 * 64))[rem] =
        ((uint2*)(lds + k * 1056))[rem];
  }
}

// iprep (+fused k1): blocks x<66 -> image transpose row; x>=66 (z==0 only)
// -> k1 hypernetwork layer 1 for d-block (x-66).  [UNCHANGED]
__global__ __launch_bounds__(256) void k_iprep(
    const float* __restrict__ image, short* __restrict__ imgt,
    const float* __restrict__ hyper, const float* __restrict__ W1,
    const float* __restrict__ b1, float* __restrict__ h_t) {
  int row = blockIdx.x;
  int g = blockIdx.y, b = blockIdx.z;
  int tid = threadIdx.x;
  if (row >= 66) {                            // ---- k1 ----
    if (b != 0) return;
    int d = (row - 66) * 256 + tid;
    if (d >= HD) return;
    const float* W1g = W1 + (size_t)g * HIN * HD + d;
    float bias = b1[g * HD + d];
    float acc[NBATCH];
#pragma unroll
    for (int bb = 0; bb < NBATCH; ++bb) acc[bb] = bias;
    for (int i = 0; i < HIN; ++i) {
      float wv = W1g[(size_t)i * HD];
#pragma unroll
      for (int bb = 0; bb < NBATCH; ++bb)
        acc[bb] = fmaf(hyper[bb * HIN + i], wv, acc[bb]);
    }
    float4* hp = (float4*)(h_t + ((size_t)g * HD + d) * 8);
    hp[0] = make_float4(fmaxf(acc[0], 0.f), fmaxf(acc[1], 0.f),
                        fmaxf(acc[2], 0.f), fmaxf(acc[3], 0.f));
    hp[1] = make_float4(fmaxf(acc[4], 0.f), fmaxf(acc[5], 0.f),
                        fmaxf(acc[6], 0.f), fmaxf(acc[7], 0.f));
    return;
  }
  int gb = g * NBATCH + b;
  short* rowp = imgt + ((size_t)gb * 66 + row) * 66 * 64;
  if (row == 0 || row == 65) {                // top/bottom halo row
    uint4 z = {0, 0, 0, 0};
    uint4* p = (uint4*)rowp;                  // 528 uint4
#pragma unroll
    for (int i = 0; i < 3; ++i) {
      int idx = tid + i * 256;
      if (idx < 528) p[idx] = z;
    }
    return;
  }
  int y = row - 1;
  __shared__ float lds[64 * 65];
  int p = tid & 63, cg = tid >> 6;
#pragma unroll
  for (int i = 0; i < 16; ++i) {
    int c = cg * 16 + i;
    lds[p * 65 + c] = image[((size_t)b * CIN + g * GIN + c) * 4096 + y * 64 + p];
  }
  __syncthreads();
  int p2 = tid >> 2, cq = tid & 3;
  unsigned short tmp[16];
#pragma unroll
  for (int i = 0; i < 16; ++i) tmp[i] = bf16rne(lds[p2 * 65 + cq * 16 + i]);
  short* dst = rowp + (p2 + 1) * 64 + cq * 16;
  *(uint4*)dst = *(uint4*)&tmp[0];
  *(uint4*)(dst + 8) = *(uint4*)&tmp[8];
  if (tid < 16) {                             // side halo col 0
    ((uint2*)rowp)[tid] = make_uint2(0, 0);
  } else if (tid < 32) {                      // side halo col 65
    ((uint2*)(rowp + 65 * 64))[tid - 16] = make_uint2(0, 0);
  }
}

// K3-MFMA v3: o-split + per-gb XCD pinning. 1024 blocks; lin&7 = XCD is
// CONSTANT per gb (all 32 blocks of one (g,b) share one XCD's L2 ->
// imgt slab + weight slab L2-resident). ms = lin>>9 selects o-half;
// acc[2][4], ~110 VGPR, launch_bounds(,4) -> 4 blocks/CU resident.
__global__ __launch_bounds__(256, 4) void k3_mfma(
    const short* __restrict__ wbf, const short* __restrict__ imgt,
    const float* __restrict__ bias_f, float* __restrict__ outbuf) {
  int lin = blockIdx.x;                 // 0..1023
  int gb = (lin & 7) * 4 + ((lin >> 3) & 3);
  int ygrp = (lin >> 5) & 15;
  int ms = lin >> 9;                    // o-half 0/1
  int g = gb >> 3, b = gb & 7;
  int tid = threadIdx.x;
  int w = tid >> 6, l = tid & 63;
  int y = ygrp * 4 + w;
  int lo = l & 15;   // A row (o), B col (x), D col
  int hi = l >> 4;   // k-chunk selector; D row-block

  const short* wgb = wbf + (size_t)gb * 9 * 4096 + ms * 32 * 64;
  const short* ibase = imgt + (((size_t)gb * 66 + y) * 66 + lo) * 64 + hi * 8;

  f32x4 acc[2][4] = {};
  bf16x8 a0[2], b0[4], a1[2], b1[4];

#define LA(dst, ks) { int s_ = (ks) >> 1, h_ = (ks) & 1;                      \
    const short* p_ = wgb + (size_t)s_ * 4096 + lo * 64 + h_ * 32 + hi * 8;   \
    _Pragma("unroll") for (int m_ = 0; m_ < 2; ++m_)                          \
      dst[m_] = *(const bf16x8*)(p_ + m_ * 1024); }
#define LB(dst, ks) { int s_ = (ks) >> 1, h_ = (ks) & 1;                      \
    int dy_ = s_ / 3, dx_ = s_ - 3 * dy_;                                     \
    const short* p_ = ibase + ((size_t)dy_ * 66 + dx_) * 64 + h_ * 32;        \
    _Pragma("unroll") for (int n_ = 0; n_ < 4; ++n_)                          \
      dst[n_] = *(const bf16x8*)(p_ + n_ * 1024); }
#define MM(aa, bb) { _Pragma("unroll") for (int m_ = 0; m_ < 2; ++m_)         \
    _Pragma("unroll") for (int n_ = 0; n_ < 4; ++n_)                          \
      acc[m_][n_] = __builtin_amdgcn_mfma_f32_16x16x32_bf16(                  \
          aa[m_], bb[n_], acc[m_][n_], 0, 0, 0); }

  LA(a0, 0) LB(b0, 0)
#pragma unroll
  for (int it = 0; it < 9; ++it) {
    LA(a1, 2 * it + 1) LB(b1, 2 * it + 1)
    MM(a0, b0)
    if (it < 8) { LA(a0, 2 * it + 2) LB(b0, 2 * it + 2) }
    MM(a1, b1)
  }

  float* op = outbuf + ((size_t)b * CIN + g * GOUT) * 4096 + y * 64;
#pragma unroll
  for (int m = 0; m < 2; ++m)
#pragma unroll
    for (int j = 0; j < 4; ++j) {
      int o = ms * 32 + m * 16 + hi * 4 + j;
      float bias = bias_f[gb * 64 + o];
#pragma unroll
      for (int n = 0; n < 4; ++n)
        op[(size_t)o * 4096 + n * 16 + lo] = acc[m][n][j] + bias;
    }
#undef LA
#undef LB
#undef MM
}

extern "C" void kernel_launch(void* const* d_in, const int* in_sizes, int n_in,
                              void* d_out, int out_size, void* d_ws, size_t ws_size,
                              hipStream_t stream) {
  const float* image = (const float*)d_in[0];
  const float* hyper = (const float*)d_in[1];
  const float* W1    = (const float*)d_in[2];
  const float* b1    = (const float*)d_in[3];
  const float* W2    = (const float*)d_in[4];
  const float* b2    = (const float*)d_in[5];
  float* out = (float*)d_out;

  float* h_t       = (float*)d_ws;                             // 74368 f32
  float* bias_f    = h_t + (size_t)G * HD * 8;                 // 2048 f32
  short* partial_bf = (short*)(bias_f + G * NBATCH * GOUT);    // 8*32*NO bf16
  short* wbf       = partial_bf + (size_t)DSPLIT * G * NBATCH * NO;
  short* imgt      = wbf + (size_t)G * NBATCH * 9 * 4096;      // 8921088 bf16

  k_iprep<<<dim3(76, G, NBATCH), 256, 0, stream>>>(image, imgt,
                                                   hyper, W1, b1, h_t);
  k2_hyper_l2<<<dim3((NO4 + 255) / 256, G, DSPLIT), 256, 0, stream>>>(h_t, W2, partial_bf);
  k_wprep<<<dim3(5, G * NBATCH), 256, 0, stream>>>(partial_bf, b2, wbf, bias_f);
  k3_mfma<<<dim3(1024), 256, 0, stream>>>(wbf, imgt, bias_f, out);
}

// Round 12
// 295.025 us; speedup vs baseline: 1.0452x; 1.0452x over previous
//
#include <hip/hip_runtime.h>

#define G 4
#define NBATCH 8
#define HIN 128
#define HD 2324
#define NW 36864
#define NO 36928   // NW + 64 biases
#define NO4 (NO / 4)        // 9232
#define GIN 64
#define GOUT 64
#define HIMG 64
#define WIMG 64
#define CIN 256
#define DSPLIT 8
#define DCHUNK 292          // 7*292 + 280 = 2324; all chunks %4==0

typedef __attribute__((ext_vector_type(8))) short bf16x8;
typedef __attribute__((ext_vector_type(4))) float f32x4;

__device__ inline unsigned short bf16rne(float f) {
  union { float f; unsigned u; } x; x.f = f;
  unsigned r = (x.u + 0x7FFF + ((x.u >> 16) & 1)) >> 16;
  return (unsigned short)r;
}
__device__ inline float bflo2f(unsigned u) {
  union { unsigned u; float f; } x; x.u = u << 16; return x.f;
}
__device__ inline float bfhi2f(unsigned u) {
  union { unsigned u; float f; } x; x.u = u & 0xFFFF0000u; return x.f;
}

#define FMA_D(wv, hoff)                                   \
  {                                                       \
    _Pragma("unroll")                                     \
    for (int b = 0; b < NBATCH; ++b) {                    \
      float hv = hh[(hoff) * 8 + b];                      \
      acc[b][0] = fmaf(hv, (wv)[0], acc[b][0]);           \
      acc[b][1] = fmaf(hv, (wv)[1], acc[b][1]);           \
      acc[b][2] = fmaf(hv, (wv)[2], acc[b][2]);           \
      acc[b][3] = fmaf(hv, (wv)[3], acc[b][3]);           \
    }                                                     \
  }

// K2: partial_bf[ds][gb][o] = bf16(sum_{d in chunk ds} h*W2)
// Non-atomic split-K; nontemporal W2 stream; bf16 partials. [UNCHANGED]
__global__ __launch_bounds__(256) void k2_hyper_l2(
    const float* __restrict__ h_t, const float* __restrict__ W2,
    short* __restrict__ partial_bf) {
  int g = blockIdx.y, ds = blockIdx.z;
  int o4 = blockIdx.x * 256 + threadIdx.x;
  bool active = (o4 < NO4);
  if (!active) o4 = NO4 - 1;
  const f32x4* W2g = (const f32x4*)(W2 + (size_t)g * HD * NO) + o4;
  const float* hg = h_t + (size_t)g * HD * 8;
  int d0 = ds * DCHUNK;
  int d1 = d0 + DCHUNK; if (d1 > HD) d1 = HD;
  int nd = d1 - d0;                        // multiple of 4

  f32x4 acc[NBATCH] = {};
  const size_t WS = NO4;
  const f32x4* Wp = W2g + (size_t)d0 * WS;
  f32x4 w0 = __builtin_nontemporal_load(Wp);
  f32x4 w1 = __builtin_nontemporal_load(Wp + WS);
  f32x4 w2 = __builtin_nontemporal_load(Wp + 2 * WS);
  f32x4 w3 = __builtin_nontemporal_load(Wp + 3 * WS);
  int dd = 0;
  for (; dd < nd - 4; dd += 4) {
    const f32x4* Wn = Wp + (size_t)(dd + 4) * WS;
    f32x4 n0 = __builtin_nontemporal_load(Wn);
    f32x4 n1 = __builtin_nontemporal_load(Wn + WS);
    f32x4 n2 = __builtin_nontemporal_load(Wn + 2 * WS);
    f32x4 n3 = __builtin_nontemporal_load(Wn + 3 * WS);
    const float* hh = hg + (size_t)(d0 + dd) * 8;   // 32 contiguous f32
    FMA_D(w0, 0) FMA_D(w1, 1) FMA_D(w2, 2) FMA_D(w3, 3)
    w0 = n0; w1 = n1; w2 = n2; w3 = n3;
  }
  {
    const float* hh = hg + (size_t)(d0 + dd) * 8;
    FMA_D(w0, 0) FMA_D(w1, 1) FMA_D(w2, 2) FMA_D(w3, 3)
  }

  if (active) {
    size_t base = ((size_t)ds * G * NBATCH + g * NBATCH) * (size_t)NO;
#pragma unroll
    for (int b = 0; b < NBATCH; ++b) {
      uint2 v;
      v.x = (unsigned)bf16rne(acc[b][0]) | ((unsigned)bf16rne(acc[b][1]) << 16);
      v.y = (unsigned)bf16rne(acc[b][2]) | ((unsigned)bf16rne(acc[b][3]) << 16);
      *(uint2*)(partial_bf + base + (size_t)b * NO + (size_t)o4 * 4) = v;
    }
  }
}

// wprep: coalesced uint2 reads of all 8 bf16 partials (+b2 f32), reduce in
// f32 regs, transpose to [k][o][c] via padded LDS, coalesced store.
// grid (5, 32): x<4 -> weights for o0=x*16; x==4 -> bias.  [UNCHANGED]
__global__ __launch_bounds__(256) void k_wprep(
    const short* __restrict__ partial_bf, const float* __restrict__ b2,
    short* __restrict__ wbf, float* __restrict__ bias_f) {
  int gb = blockIdx.y;
  int g = gb >> 3;
  int tid = threadIdx.x;
  if (blockIdx.x == 4) {
    if (tid < GOUT) {
      float s = b2[(size_t)g * NO + NW + tid];
#pragma unroll
      for (int ds = 0; ds < DSPLIT; ++ds) {
        unsigned short pv = (unsigned short)
            partial_bf[((size_t)ds * G * NBATCH + gb) * NO + NW + tid];
        s += bflo2f(pv);
      }
      bias_f[gb * GOUT + tid] = s;
    }
    return;
  }
  __shared__ short lds[9 * 1056];          // padded k-planes
  int o0 = blockIdx.x * 16;
  const f32x4* b2p = (const f32x4*)(b2 + (size_t)g * NO) + o0 * 144;
  const uint2* pbase = (const uint2*)partial_bf + (size_t)gb * NO4 + o0 * 144;
#pragma unroll
  for (int j = 0; j < 9; ++j) {
    int idx4 = tid + j * 256;              // [0, 2304)
    f32x4 s = b2p[idx4];
#pragma unroll
    for (int ds = 0; ds < DSPLIT; ++ds) {
      uint2 v = pbase[(size_t)ds * G * NBATCH * NO4 + idx4];  // coalesced 8B
      s[0] += bflo2f(v.x); s[1] += bfhi2f(v.x);
      s[2] += bflo2f(v.y); s[3] += bfhi2f(v.y);
    }
    int flbase = idx4 * 4;                 // local f in [0, 9216)
#pragma unroll
    for (int e = 0; e < 4; ++e) {
      int fl = flbase + e;
      int ol = fl / 576;
      int rest = fl - ol * 576;
      int c = rest / 9, k = rest - c * 9;
      lds[k * 1056 + ol * 64 + c] = (short)bf16rne(s[e]);
    }
  }
  __syncthreads();
  short* wout = wbf + (size_t)gb * NW;     // [k][o][c], k-plane = 4096 shorts
#pragma unroll
  for (int j = 0; j < 9; ++j) {
    int u = tid + j * 256;                 // uint2 index [0, 2304)
    int k = u >> 8, rem = u & 255;         // 256 uint2 per k-plane (16 o's)
    ((uint2*)(wout + (size_t)k * 4096 + o0 * 64))[rem] =
        ((uint2*)(lds + k * 1056))[rem];
  }
}

// iprep (+fused k1): blocks x<66 -> image transpose row; x>=66 (z==0 only)
// -> k1 hypernetwork layer 1 for d-block (x-66).  [UNCHANGED]
__global__ __launch_bounds__(256) void k_iprep(
    const float* __restrict__ image, short* __restrict__ imgt,
    const float* __restrict__ hyper, const float* __restrict__ W1,
    const float* __restrict__ b1, float* __restrict__ h_t) {
  int row = blockIdx.x;
  int g = blockIdx.y, b = blockIdx.z;
  int tid = threadIdx.x;
  if (row >= 66) {                            // ---- k1 ----
    if (b != 0) return;
    int d = (row - 66) * 256 + tid;
    if (d >= HD) return;
    const float* W1g = W1 + (size_t)g * HIN * HD + d;
    float bias = b1[g * HD + d];
    float acc[NBATCH];
#pragma unroll
    for (int bb = 0; bb < NBATCH; ++bb) acc[bb] = bias;
    for (int i = 0; i < HIN; ++i) {
      float wv = W1g[(size_t)i * HD];
#pragma unroll
      for (int bb = 0; bb < NBATCH; ++bb)
        acc[bb] = fmaf(hyper[bb * HIN + i], wv, acc[bb]);
    }
    float4* hp = (float4*)(h_t + ((size_t)g * HD + d) * 8);
    hp[0] = make_float4(fmaxf(acc[0], 0.f), fmaxf(acc[1], 0.f),
                        fmaxf(acc[2], 0.f), fmaxf(acc[3], 0.f));
    hp[1] = make_float4(fmaxf(acc[4], 0.f), fmaxf(acc[5], 0.f),
                        fmaxf(acc[6], 0.f), fmaxf(acc[7], 0.f));
    return;
  }
  int gb = g * NBATCH + b;
  short* rowp = imgt + ((size_t)gb * 66 + row) * 66 * 64;
  if (row == 0 || row == 65) {                // top/bottom halo row
    uint4 z = {0, 0, 0, 0};
    uint4* p = (uint4*)rowp;                  // 528 uint4
#pragma unroll
    for (int i = 0; i < 3; ++i) {
      int idx = tid + i * 256;
      if (idx < 528) p[idx] = z;
    }
    return;
  }
  int y = row - 1;
  __shared__ float lds[64 * 65];
  int p = tid & 63, cg = tid >> 6;
#pragma unroll
  for (int i = 0; i < 16; ++i) {
    int c = cg * 16 + i;
    lds[p * 65 + c] = image[((size_t)b * CIN + g * GIN + c) * 4096 + y * 64 + p];
  }
  __syncthreads();
  int p2 = tid >> 2, cq = tid & 3;
  unsigned short tmp[16];
#pragma unroll
  for (int i = 0; i < 16; ++i) tmp[i] = bf16rne(lds[p2 * 65 + cq * 16 + i]);
  short* dst = rowp + (p2 + 1) * 64 + cq * 16;
  *(uint4*)dst = *(uint4*)&tmp[0];
  *(uint4*)(dst + 8) = *(uint4*)&tmp[8];
  if (tid < 16) {                             // side halo col 0
    ((uint2*)rowp)[tid] = make_uint2(0, 0);
  } else if (tid < 32) {                      // side halo col 65
    ((uint2*)(rowp + 65 * 64))[tid - 16] = make_uint2(0, 0);
  }
}

// K3-MFMA (round-10 winner, reverted): full 64-o tile per wave (4x4 acc),
// 512 blocks, per-gb XCD pinning: lin&7 = XCD constant per gb -> imgt slab
// + weight slab L2-resident on one XCD. Wave = one row y; 1-deep prefetch.
__global__ __launch_bounds__(256) void k3_mfma(
    const short* __restrict__ wbf, const short* __restrict__ imgt,
    const float* __restrict__ bias_f, float* __restrict__ outbuf) {
  int lin = blockIdx.x;                 // 0..511
  int gb = (lin & 7) * 4 + ((lin >> 3) & 3);
  int ygrp = lin >> 5;
  int g = gb >> 3, b = gb & 7;
  int tid = threadIdx.x;
  int w = tid >> 6, l = tid & 63;
  int y = ygrp * 4 + w;
  int lo = l & 15;   // A row (o), B col (x), D col
  int hi = l >> 4;   // k-chunk selector; D row-block

  const short* wgb = wbf + (size_t)gb * 9 * 4096;   // [tap][o][c]
  const short* ibase = imgt + (((size_t)gb * 66 + y) * 66 + lo) * 64 + hi * 8;

  f32x4 acc[4][4] = {};
  bf16x8 a0[4], b0[4], a1[4], b1[4];

#define LA(dst, ks) { int s_ = (ks) >> 1, h_ = (ks) & 1;                      \
    const short* p_ = wgb + (size_t)s_ * 4096 + lo * 64 + h_ * 32 + hi * 8;   \
    _Pragma("unroll") for (int m_ = 0; m_ < 4; ++m_)                          \
      dst[m_] = *(const bf16x8*)(p_ + m_ * 1024); }
#define LB(dst, ks) { int s_ = (ks) >> 1, h_ = (ks) & 1;                      \
    int dy_ = s_ / 3, dx_ = s_ - 3 * dy_;                                     \
    const short* p_ = ibase + ((size_t)dy_ * 66 + dx_) * 64 + h_ * 32;        \
    _Pragma("unroll") for (int n_ = 0; n_ < 4; ++n_)                          \
      dst[n_] = *(const bf16x8*)(p_ + n_ * 1024); }
#define MM(aa, bb) { _Pragma("unroll") for (int m_ = 0; m_ < 4; ++m_)         \
    _Pragma("unroll") for (int n_ = 0; n_ < 4; ++n_)                          \
      acc[m_][n_] = __builtin_amdgcn_mfma_f32_16x16x32_bf16(                  \
          aa[m_], bb[n_], acc[m_][n_], 0, 0, 0); }

  LA(a0, 0) LB(b0, 0)
#pragma unroll
  for (int it = 0; it < 9; ++it) {
    LA(a1, 2 * it + 1) LB(b1, 2 * it + 1)
    MM(a0, b0)
    if (it < 8) { LA(a0, 2 * it + 2) LB(b0, 2 * it + 2) }
    MM(a1, b1)
  }

  float* op = outbuf + ((size_t)b * CIN + g * GOUT) * 4096 + y * 64;
#pragma unroll
  for (int m = 0; m < 4; ++m)
#pragma unroll
    for (int j = 0; j < 4; ++j) {
      int o = m * 16 + hi * 4 + j;
      float bias = bias_f[gb * 64 + o];
#pragma unroll
      for (int n = 0; n < 4; ++n)
        op[(size_t)o * 4096 + n * 16 + lo] = acc[m][n][j] + bias;
    }
#undef LA
#undef LB
#undef MM
}

extern "C" void kernel_launch(void* const* d_in, const int* in_sizes, int n_in,
                              void* d_out, int out_size, void* d_ws, size_t ws_size,
                              hipStream_t stream) {
  const float* image = (const float*)d_in[0];
  const float* hyper = (const float*)d_in[1];
  const float* W1    = (const float*)d_in[2];
  const float* b1    = (const float*)d_in[3];
  const float* W2    = (const float*)d_in[4];
  const float* b2    = (const float*)d_in[5];
  float* out = (float*)d_out;

  float* h_t       = (float*)d_ws;                             // 74368 f32
  float* bias_f    = h_t + (size_t)G * HD * 8;                 // 2048 f32
  short* partial_bf = (short*)(bias_f + G * NBATCH * GOUT);    // 8*32*NO bf16
  short* wbf       = partial_bf + (size_t)DSPLIT * G * NBATCH * NO;
  short* imgt      = wbf + (size_t)G * NBATCH * 9 * 4096;      // 8921088 bf16

  k_iprep<<<dim3(76, G, NBATCH), 256, 0, stream>>>(image, imgt,
                                                   hyper, W1, b1, h_t);
  k2_hyper_l2<<<dim3((NO4 + 255) / 256, G, DSPLIT), 256, 0, stream>>>(h_t, W2, partial_bf);
  k_wprep<<<dim3(5, G * NBATCH), 256, 0, stream>>>(partial_bf, b2, wbf, bias_f);
  k3_mfma<<<dim3(512), 256, 0, stream>>>(wbf, imgt, bias_f, out);
}